// Round 1
// baseline (226.634 us; speedup 1.0000x reference)
//
#include <hip/hip_runtime.h>
#include <stdint.h>

typedef unsigned long long ull;

#define NA 8400
#define NB 32
#define KTOP 300
#define NC 80
#define CH 33          // 256*33 = 8448 >= 8400

// out layout: boxes_yxyx @0 ; in_zone @38400 ; scores @48000 ; classes @57600 ;
//             centers_yx @67200 ; keep @86400 ; total 96000 floats
#define O1 38400
#define O2 48000
#define O3 57600
#define O4 67200
#define O5 86400

// ---------------- A: per-anchor score key (memory-bound, unchanged) ----------------
__global__ __launch_bounds__(256) void score_kernel(const float* __restrict__ pred,
                                                    uint32_t* __restrict__ keys) {
    __shared__ float sP[128 * 85];
    const int blk = blockIdx.x;                       // 2100 blocks * 128 anchors
    const float4* g4 = (const float4*)(pred + (size_t)blk * 128 * 85);
    float4* l4 = (float4*)sP;
    for (int i = threadIdx.x; i < (128 * 85 / 4); i += 256) l4[i] = g4[i];
    __syncthreads();
    const int t = threadIdx.x;
    if (t < 128) {
        const float* p = sP + t * 85;
        float obj = p[4];
        // 4-way interleaved max to break the 80-deep dependence chain (no NaN in inputs)
        float b0 = p[5], b1 = p[6], b2 = p[7], b3 = p[8];
        #pragma unroll
        for (int c = 4; c < NC; c += 4) {
            b0 = fmaxf(b0, p[5 + c]);
            b1 = fmaxf(b1, p[6 + c]);
            b2 = fmaxf(b2, p[7 + c]);
            b3 = fmaxf(b3, p[8 + c]);
        }
        float best = fmaxf(fmaxf(b0, b1), fmaxf(b2, b3));
        float sc = obj * best;
        uint32_t u = (sc >= 0.2f) ? (__float_as_uint(sc) | 0x80000000u) : 0x007FFFFFu;
        keys[(size_t)blk * 128 + t] = u;
    }
}

// ---------------- B: fused per-batch select + IoU masks + NMS + all outputs ----------------
// One block per batch. All intermediates live in LDS; no global round-trips.
__global__ __launch_bounds__(256) void batch_kernel(const float* __restrict__ pred,
                                                    const float* __restrict__ zone,
                                                    const uint32_t* __restrict__ keys,
                                                    float* __restrict__ out) {
    #pragma clang fp contract(off)
    // keys region is dead after compaction -> reuse it for boxes + suppression masks
    __shared__ union {
        uint32_t keys[8448];
        struct {
            float b0[KTOP], b1[KTOP], b2[KTOP], b3[KTOP];   // 4800 B
            ull mask[KTOP * 5];                             // 12000 B
        } late;
    } u;
    __shared__ ull sSel[KTOP];
    __shared__ ull sSorted[KTOP];
    __shared__ uint32_t sH[8 * 257];    // 8 copies, stride 257 -> copies of a bucket hit different banks
    __shared__ uint32_t sTot[4];
    __shared__ uint32_t sBc[2];
    __shared__ int sCnt;
    __shared__ ull sKeepF[5];
    __shared__ float sZone[16];

    const int b = blockIdx.x;
    const int t = threadIdx.x;
    const int lane = t & 63;
    const int wv = t >> 6;
    const int hc = t >> 5;              // 8 histogram copies (one per 32 threads)

    {   // ---- load keys (vectorized; batch base is 16B-aligned: 33600 % 16 == 0) ----
        const uint4* g4 = (const uint4*)(keys + (size_t)b * NA);
        uint4* l4 = (uint4*)u.keys;
        for (int i = t; i < NA / 4; i += 256) l4[i] = g4[i];
        for (int e = NA + t; e < 8448; e += 256) u.keys[e] = 0u;
    }
    if (t < 16) sZone[t] = zone[t];
    if (t == 0) sCnt = 0;
    __syncthreads();

    // ---- radix select: exact 300th-largest key (4 rounds, wave-shfl suffix scan) ----
    uint32_t prefix = 0, r = KTOP;
    const int beg = t * CH;
    const int end = (beg + CH < NA) ? beg + CH : NA;
    for (int round = 0; round < 4; ++round) {
        const int shift = 24 - 8 * round;
        for (int i = t; i < 8 * 257; i += 256) sH[i] = 0u;
        __syncthreads();
        const uint32_t pmask = (round == 0) ? 0u : (0xFFFFFFFFu << (shift + 8));
        for (int e = beg; e < end; ++e) {
            uint32_t k = u.keys[e];
            if ((k & pmask) == (prefix & pmask))
                atomicAdd(&sH[hc * 257 + ((k >> shift) & 0xFFu)], 1u);
        }
        __syncthreads();
        uint32_t v = 0;
        #pragma unroll
        for (int c = 0; c < 8; ++c) v += sH[c * 257 + t];
        // in-wave inclusive suffix scan over bins (lane L holds sum of bins L..63 of its wave)
        uint32_t s = v;
        #pragma unroll
        for (int off = 1; off < 64; off <<= 1) {
            uint32_t o = __shfl_down(s, off, 64);
            if (lane + off < 64) s += o;
        }
        if (lane == 0) sTot[wv] = s;
        __syncthreads();
        uint32_t S = s;
        #pragma unroll
        for (int w2 = 0; w2 < 4; ++w2) if (w2 > wv) S += sTot[w2];
        uint32_t above = S - v;          // suffix sum strictly above bin t
        if (above < r && S >= r) {
            sBc[0] = prefix | ((uint32_t)t << shift);
            sBc[1] = r - above;
        }
        __syncthreads();
        prefix = sBc[0]; r = sBc[1];
        // safe: next writes to sH after this read, next writes to sBc/sTot only after
        // the next round's zero+count barriers.
    }
    const uint32_t kth = prefix;
    const uint32_t rem = r;
    const uint32_t cntgt = KTOP - rem;

    // ---- compact the top-300 set into sSel (unordered for >, index-ordered for ==) ----
    {
        uint32_t eqc = 0;
        for (int e = beg; e < end; ++e) {
            uint32_t k = u.keys[e];
            if (k > kth) {
                int p = atomicAdd(&sCnt, 1);
                sSel[p] = ((ull)k << 32) | (ull)(0xFFFFFFFFu - (uint32_t)e);
            } else if (k == kth) eqc++;
        }
        // in-wave inclusive prefix scan of equal-counts (thread order == ascending anchor order)
        uint32_t ps = eqc;
        #pragma unroll
        for (int off = 1; off < 64; off <<= 1) {
            uint32_t o = __shfl_up(ps, off, 64);
            if (lane >= off) ps += o;
        }
        if (lane == 63) sTot[wv] = ps;
        __syncthreads();
        uint32_t off0 = ps - eqc;        // exclusive within wave
        #pragma unroll
        for (int w2 = 0; w2 < 4; ++w2) if (w2 < wv) off0 += sTot[w2];
        for (int e = beg; e < end; ++e) {
            uint32_t k = u.keys[e];
            if (k == kth) {
                if (off0 < rem)
                    sSel[cntgt + off0] = ((ull)k << 32) | (ull)(0xFFFFFFFFu - (uint32_t)e);
                off0++;
            }
        }
        __syncthreads();                 // last read of u.keys is above
    }

    // ---- rank sort: 64-bit entries are unique -> ranks are a permutation ----
    {
        ull my0 = sSel[t];
        ull my1 = (t < KTOP - 256) ? sSel[256 + t] : 0ull;
        int r0 = 0, r1 = 0;
        for (int j = 0; j < KTOP; ++j) {
            ull v = sSel[j];             // broadcast read
            r0 += (v > my0) ? 1 : 0;
            r1 += (v > my1) ? 1 : 0;
        }
        sSorted[r0] = my0;
        if (t < KTOP - 256) sSorted[r1] = my1;
        __syncthreads();
    }

    // ---- gather boxes for the 300 selected anchors (keys region now reused) ----
    for (int i = t; i < KTOP; i += 256) {
        uint32_t a = 0xFFFFFFFFu - (uint32_t)sSorted[i];
        const float* p = pred + ((size_t)b * NA + a) * 85;
        float x = p[0], y = p[1], w = p[2], h = p[3];
        float hw = w * 0.5f, hh = h * 0.5f;
        u.late.b0[i] = x - hw; u.late.b1[i] = y - hh;
        u.late.b2[i] = x + hw; u.late.b3[i] = y + hh;
    }
    __syncthreads();

    // ---- IoU suppression masks (1500 words, all in LDS) ----
    for (int role = 0; role < 5; ++role) {
        const int j0 = role * 64;
        int jmax = j0 + 64; if (jmax > KTOP) jmax = KTOP;
        for (int i = t; i < KTOP; i += 256) {
            float x1 = u.late.b0[i], y1 = u.late.b1[i], x2 = u.late.b2[i], y2 = u.late.b3[i];
            float ai = fmaxf(x2 - x1, 0.0f) * fmaxf(y2 - y1, 0.0f);
            ull bits = 0ull;
            int jbeg = (j0 > i + 1) ? j0 : (i + 1);
            for (int j = jbeg; j < jmax; ++j) {
                float bx1 = u.late.b0[j], by1 = u.late.b1[j], bx2 = u.late.b2[j], by2 = u.late.b3[j];
                float aj = fmaxf(bx2 - bx1, 0.0f) * fmaxf(by2 - by1, 0.0f);
                float iw = fminf(x2, bx2) - fmaxf(x1, bx1); iw = fmaxf(iw, 0.0f);
                float ih = fminf(y2, by2) - fmaxf(y1, by1); ih = fmaxf(ih, 0.0f);
                float inter = iw * ih;
                float den = ai + aj;     // mirror reference op order exactly
                den = den - inter;
                den = den + 1e-9f;
                float iou = inter / den;
                if (iou > 0.45f) bits |= (1ull << (j - j0));
            }
            u.late.mask[i * 5 + role] = bits;
        }
    }
    __syncthreads();

    // ---- wave 0: greedy NMS.  waves 1-3 (independent): detail gather + outputs ----
    if (wv == 0) {
        ull rm[5][5];
        ull kw[5];
        #pragma unroll
        for (int w = 0; w < 5; ++w) {
            int i = w * 64 + lane;
            bool f = (i < KTOP) && (((uint32_t)(sSorted[i] >> 32)) > 0x007FFFFFu);
            kw[w] = __ballot(f);         // keep-init, replicated in every lane
            #pragma unroll
            for (int ww = 0; ww < 5; ++ww)
                rm[w][ww] = (i < KTOP) ? u.late.mask[i * 5 + ww] : 0ull;
        }
        #pragma unroll
        for (int w = 0; w < 5; ++w) {
            ull cur = kw[w];
            while (cur) {
                int ib = __builtin_ctzll(cur);      // accepted box i = w*64+ib
                ull m0 = __shfl(rm[w][0], ib);
                ull m1 = __shfl(rm[w][1], ib);
                ull m2 = __shfl(rm[w][2], ib);
                ull m3 = __shfl(rm[w][3], ib);
                ull m4 = __shfl(rm[w][4], ib);
                kw[0] &= ~m0; kw[1] &= ~m1; kw[2] &= ~m2; kw[3] &= ~m3; kw[4] &= ~m4;
                ull done = (ib == 63) ? 0ull : (~0ull << (ib + 1));
                cur = kw[w] & done;
            }
        }
        if (lane == 0) {
            #pragma unroll
            for (int w = 0; w < 5; ++w) sKeepF[w] = kw[w];
        }
    } else {
        const size_t bo = (size_t)b * KTOP;
        for (int i = t - 64; i < KTOP; i += 192) {
            uint32_t a = 0xFFFFFFFFu - (uint32_t)sSorted[i];
            const float* p = pred + ((size_t)b * NA + a) * 85;
            float x = p[0], y = p[1], w = p[2], h = p[3], obj = p[4];
            float best = p[5]; int bc = 0;
            for (int c = 1; c < NC; ++c) {     // sequential: argmax must keep FIRST max
                float v = p[5 + c];
                if (v > best) { best = v; bc = c; }
            }
            float hw = w * 0.5f, hh = h * 0.5f;
            float x1 = x - hw, y1 = y - hh, x2 = x + hw, y2 = y + hh;
            out[(bo + i) * 4 + 0] = y1;
            out[(bo + i) * 4 + 1] = x1;
            out[(bo + i) * 4 + 2] = y2;
            out[(bo + i) * 4 + 3] = x2;
            out[O4 + (bo + i) * 2 + 0] = (y1 + y2) * 0.5f;
            out[O4 + (bo + i) * 2 + 1] = (x1 + x2) * 0.5f;
            out[O2 + bo + i] = fmaxf(obj, best);
            out[O3 + bo + i] = (float)bc;
        }
    }
    __syncthreads();

    // ---- keep + in_zone (centers recomputed from LDS boxes: bit-identical ops) ----
    const size_t bo = (size_t)b * KTOP;
    for (int i = t; i < KTOP; i += 256) {
        int kp = (int)((sKeepF[i >> 6] >> (i & 63)) & 1ull);
        float cy = (u.late.b1[i] + u.late.b3[i]) * 0.5f;
        float cx = (u.late.b0[i] + u.late.b2[i]) * 0.5f;
        int cnt = 0;
        #pragma unroll
        for (int e = 0; e < 8; ++e) {
            float xi = sZone[2 * e], yi = sZone[2 * e + 1];
            int ep = (e + 7) & 7;               // zr = roll(zone, 1)
            float xj = sZone[2 * ep], yj = sZone[2 * ep + 1];
            bool gyi = yi > cy, gyj = yj > cy;
            if (gyi != gyj) {
                float gx = (xj - xi) * (cy - yi) / (yj - yi) + xi;
                if (gx > cx) cnt++;
            }
        }
        int inz = (((cnt & 1) != 0) && kp) ? 1 : 0;
        out[O1 + bo + i] = (float)inz;
        out[O5 + bo + i] = (float)kp;
    }
}

extern "C" void kernel_launch(void* const* d_in, const int* in_sizes, int n_in,
                              void* d_out, int out_size, void* d_ws, size_t ws_size,
                              hipStream_t stream) {
    const float* pred = (const float*)d_in[0];   // (32,8400,85) fp32
    const float* zone = (const float*)d_in[1];   // (8,2) fp32
    float* out = (float*)d_out;                  // 96000 fp32
    uint32_t* keys = (uint32_t*)d_ws;            // 32*8400 u32 = 1.075 MB

    score_kernel<<<(NB * NA) / 128, 256, 0, stream>>>(pred, keys);
    batch_kernel<<<NB, 256, 0, stream>>>(pred, zone, keys, out);
}

// Round 2
// 200.307 us; speedup vs baseline: 1.1314x; 1.1314x over previous
//
#include <hip/hip_runtime.h>
#include <stdint.h>

typedef unsigned long long ull;

#define NA 8400
#define NB 32
#define KTOP 300
#define NC 80
#define CH 9           // 1024*9 = 9216 >= 8400
#define NCOPY 16       // histogram copies (one per wave)
#define HSTRIDE 257    // copies of one bucket land in different banks

// out layout: boxes_yxyx @0 ; in_zone @38400 ; scores @48000 ; classes @57600 ;
//             centers_yx @67200 ; keep @86400 ; total 96000 floats
#define O1 38400
#define O2 48000
#define O3 57600
#define O4 67200
#define O5 86400

// ---------------- A: per-anchor score key (memory-bound, unchanged) ----------------
__global__ __launch_bounds__(256) void score_kernel(const float* __restrict__ pred,
                                                    uint32_t* __restrict__ keys) {
    __shared__ float sP[128 * 85];
    const int blk = blockIdx.x;                       // 2100 blocks * 128 anchors
    const float4* g4 = (const float4*)(pred + (size_t)blk * 128 * 85);
    float4* l4 = (float4*)sP;
    for (int i = threadIdx.x; i < (128 * 85 / 4); i += 256) l4[i] = g4[i];
    __syncthreads();
    const int t = threadIdx.x;
    if (t < 128) {
        const float* p = sP + t * 85;
        float obj = p[4];
        // 4-way interleaved max to break the 80-deep dependence chain (no NaN in inputs)
        float b0 = p[5], b1 = p[6], b2 = p[7], b3 = p[8];
        #pragma unroll
        for (int c = 4; c < NC; c += 4) {
            b0 = fmaxf(b0, p[5 + c]);
            b1 = fmaxf(b1, p[6 + c]);
            b2 = fmaxf(b2, p[7 + c]);
            b3 = fmaxf(b3, p[8 + c]);
        }
        float best = fmaxf(fmaxf(b0, b1), fmaxf(b2, b3));
        float sc = obj * best;
        uint32_t u = (sc >= 0.2f) ? (__float_as_uint(sc) | 0x80000000u) : 0x007FFFFFu;
        keys[(size_t)blk * 128 + t] = u;
    }
}

// ---------------- B: fused per-batch pipeline, 1024 threads (4 waves/SIMD) ----------------
__global__ __launch_bounds__(1024) void batch_kernel(const float* __restrict__ pred,
                                                     const float* __restrict__ zone,
                                                     const uint32_t* __restrict__ keys,
                                                     float* __restrict__ out) {
    #pragma clang fp contract(off)
    // keys region is dead after compaction -> reuse it for boxes + suppression masks
    __shared__ union {
        uint32_t keys[8448];
        struct {
            float b0[KTOP], b1[KTOP], b2[KTOP], b3[KTOP];   // 4800 B
            ull mask[KTOP * 5];                             // 12000 B
        } late;
    } u;
    __shared__ ull sSel[KTOP];
    __shared__ ull sSorted[KTOP];
    __shared__ uint32_t sH[NCOPY * HSTRIDE];
    __shared__ uint32_t sWTot[16];      // per-wave totals for 1024-thread prefix scan
    __shared__ uint32_t sTot4[4];       // per-wave totals for 256-bin suffix scan
    __shared__ uint32_t sBc[2];
    __shared__ int sCnt;
    __shared__ ull sKeepF[5];
    __shared__ float sZone[16];

    const int b = blockIdx.x;
    const int t = threadIdx.x;
    const int lane = t & 63;
    const int wv = t >> 6;              // 0..15; also the histogram copy id

    {   // ---- load keys (vectorized; batch base is 16B-aligned: 33600 % 16 == 0) ----
        const uint4* g4 = (const uint4*)(keys + (size_t)b * NA);
        uint4* l4 = (uint4*)u.keys;
        for (int i = t; i < NA / 4; i += 1024) l4[i] = g4[i];
    }
    if (t < 16) sZone[t] = zone[t];
    if (t == 0) sCnt = 0;
    __syncthreads();

    // ---- radix select: exact 300th-largest key (4 rounds, shfl scans) ----
    uint32_t prefix = 0, r = KTOP;
    const int beg = t * CH;
    const int end = (beg + CH < NA) ? beg + CH : NA;
    for (int round = 0; round < 4; ++round) {
        const int shift = 24 - 8 * round;
        for (int i = t; i < NCOPY * HSTRIDE; i += 1024) sH[i] = 0u;
        __syncthreads();
        const uint32_t pmask = (round == 0) ? 0u : (0xFFFFFFFFu << (shift + 8));
        for (int e = beg; e < end; ++e) {
            uint32_t k = u.keys[e];
            if ((k & pmask) == (prefix & pmask))
                atomicAdd(&sH[wv * HSTRIDE + ((k >> shift) & 0xFFu)], 1u);
        }
        __syncthreads();
        uint32_t v = 0, s = 0;
        if (t < 256) {
            #pragma unroll
            for (int c = 0; c < NCOPY; ++c) v += sH[c * HSTRIDE + t];
            // in-wave inclusive suffix scan over bins (lane L = sum of bins L..63 of wave)
            s = v;
            #pragma unroll
            for (int off = 1; off < 64; off <<= 1) {
                uint32_t o = __shfl_down(s, off, 64);
                if (lane + off < 64) s += o;
            }
            if (lane == 0) sTot4[t >> 6] = s;
        }
        __syncthreads();
        if (t < 256) {
            uint32_t S = s;
            const int w4 = t >> 6;
            #pragma unroll
            for (int w2 = 0; w2 < 4; ++w2) if (w2 > w4) S += sTot4[w2];
            uint32_t above = S - v;      // suffix sum strictly above bin t
            if (above < r && S >= r) {
                sBc[0] = prefix | ((uint32_t)t << shift);
                sBc[1] = r - above;
            }
        }
        __syncthreads();
        prefix = sBc[0]; r = sBc[1];
        // sBc rewritten only after >=2 barriers next round; sH/sTot4 likewise. safe.
    }
    const uint32_t kth = prefix;
    const uint32_t rem = r;
    const uint32_t cntgt = KTOP - rem;

    // ---- compact the top-300 set into sSel (unordered for >, index-ordered for ==) ----
    {
        uint32_t eqc = 0;
        for (int e = beg; e < end; ++e) {
            uint32_t k = u.keys[e];
            if (k > kth) {
                int p = atomicAdd(&sCnt, 1);
                sSel[p] = ((ull)k << 32) | (ull)(0xFFFFFFFFu - (uint32_t)e);
            } else if (k == kth) eqc++;
        }
        // inclusive prefix scan of equal-counts across 1024 threads
        // (thread order == ascending anchor order; matches top_k tie-break)
        uint32_t ps = eqc;
        #pragma unroll
        for (int off = 1; off < 64; off <<= 1) {
            uint32_t o = __shfl_up(ps, off, 64);
            if (lane >= off) ps += o;
        }
        if (lane == 63) sWTot[wv] = ps;
        __syncthreads();
        uint32_t off0 = ps - eqc;        // exclusive within wave
        #pragma unroll
        for (int w2 = 0; w2 < 16; ++w2) if (w2 < wv) off0 += sWTot[w2];
        for (int e = beg; e < end; ++e) {
            uint32_t k = u.keys[e];
            if (k == kth) {
                if (off0 < rem)
                    sSel[cntgt + off0] = ((ull)k << 32) | (ull)(0xFFFFFFFFu - (uint32_t)e);
                off0++;
            }
        }
        __syncthreads();                 // last read of u.keys is above
    }

    // ---- rank sort: 64-bit entries are unique -> ranks are a permutation ----
    if (t < KTOP) {
        ull my = sSel[t];
        int rk = 0;
        for (int j = 0; j < KTOP; ++j) {
            ull v = sSel[j];             // broadcast read
            rk += (v > my) ? 1 : 0;
        }
        sSorted[rk] = my;
    }
    __syncthreads();

    // ---- single gather pass: boxes -> LDS, all keep-independent outputs -> global ----
    const size_t bo = (size_t)b * KTOP;
    if (t < KTOP) {
        uint32_t a = 0xFFFFFFFFu - (uint32_t)sSorted[t];
        const float* p = pred + ((size_t)b * NA + a) * 85;
        float x = p[0], y = p[1], w = p[2], h = p[3], obj = p[4];
        float best = p[5]; int bc = 0;
        for (int c = 1; c < NC; ++c) {   // sequential: argmax must keep FIRST max
            float v = p[5 + c];
            if (v > best) { best = v; bc = c; }
        }
        float hw = w * 0.5f, hh = h * 0.5f;
        float x1 = x - hw, y1 = y - hh, x2 = x + hw, y2 = y + hh;
        u.late.b0[t] = x1; u.late.b1[t] = y1;
        u.late.b2[t] = x2; u.late.b3[t] = y2;
        out[(bo + t) * 4 + 0] = y1;
        out[(bo + t) * 4 + 1] = x1;
        out[(bo + t) * 4 + 2] = y2;
        out[(bo + t) * 4 + 3] = x2;
        out[O4 + (bo + t) * 2 + 0] = (y1 + y2) * 0.5f;
        out[O4 + (bo + t) * 2 + 1] = (x1 + x2) * 0.5f;
        out[O2 + bo + t] = fmaxf(obj, best);
        out[O3 + bo + t] = (float)bc;
    }
    __syncthreads();

    // ---- IoU suppression masks: 1500 (i,role) words over 1024 threads ----
    for (int p = t; p < KTOP * 5; p += 1024) {
        const int i = p / 5;
        const int role = p % 5;
        const int j0 = role * 64;
        int jmax = j0 + 64; if (jmax > KTOP) jmax = KTOP;
        float x1 = u.late.b0[i], y1 = u.late.b1[i], x2 = u.late.b2[i], y2 = u.late.b3[i];
        float ai = fmaxf(x2 - x1, 0.0f) * fmaxf(y2 - y1, 0.0f);
        ull bits = 0ull;
        int jbeg = (j0 > i + 1) ? j0 : (i + 1);
        for (int j = jbeg; j < jmax; ++j) {
            float bx1 = u.late.b0[j], by1 = u.late.b1[j], bx2 = u.late.b2[j], by2 = u.late.b3[j];
            float aj = fmaxf(bx2 - bx1, 0.0f) * fmaxf(by2 - by1, 0.0f);
            float iw = fminf(x2, bx2) - fmaxf(x1, bx1); iw = fmaxf(iw, 0.0f);
            float ih = fminf(y2, by2) - fmaxf(y1, by1); ih = fmaxf(ih, 0.0f);
            float inter = iw * ih;
            float den = ai + aj;         // mirror reference op order exactly
            den = den - inter;
            den = den + 1e-9f;
            float iou = inter / den;
            if (iou > 0.45f) bits |= (1ull << (j - j0));
        }
        u.late.mask[p] = bits;           // p == i*5 + role
    }
    __syncthreads();

    // ---- wave 0: greedy NMS ----
    if (wv == 0) {
        ull rm[5][5];
        ull kw[5];
        #pragma unroll
        for (int w = 0; w < 5; ++w) {
            int i = w * 64 + lane;
            bool f = (i < KTOP) && (((uint32_t)(sSorted[i] >> 32)) > 0x007FFFFFu);
            kw[w] = __ballot(f);         // keep-init, replicated in every lane
            #pragma unroll
            for (int ww = 0; ww < 5; ++ww)
                rm[w][ww] = (i < KTOP) ? u.late.mask[i * 5 + ww] : 0ull;
        }
        #pragma unroll
        for (int w = 0; w < 5; ++w) {
            ull cur = kw[w];
            while (cur) {
                int ib = __builtin_ctzll(cur);      // accepted box i = w*64+ib
                ull m0 = __shfl(rm[w][0], ib);
                ull m1 = __shfl(rm[w][1], ib);
                ull m2 = __shfl(rm[w][2], ib);
                ull m3 = __shfl(rm[w][3], ib);
                ull m4 = __shfl(rm[w][4], ib);
                kw[0] &= ~m0; kw[1] &= ~m1; kw[2] &= ~m2; kw[3] &= ~m3; kw[4] &= ~m4;
                ull done = (ib == 63) ? 0ull : (~0ull << (ib + 1));
                cur = kw[w] & done;
            }
        }
        if (lane == 0) {
            #pragma unroll
            for (int w = 0; w < 5; ++w) sKeepF[w] = kw[w];
        }
    }
    __syncthreads();

    // ---- keep + in_zone (centers recomputed from LDS boxes: bit-identical ops) ----
    if (t < KTOP) {
        int kp = (int)((sKeepF[t >> 6] >> (t & 63)) & 1ull);
        float cy = (u.late.b1[t] + u.late.b3[t]) * 0.5f;
        float cx = (u.late.b0[t] + u.late.b2[t]) * 0.5f;
        int cnt = 0;
        #pragma unroll
        for (int e = 0; e < 8; ++e) {
            float xi = sZone[2 * e], yi = sZone[2 * e + 1];
            int ep = (e + 7) & 7;               // zr = roll(zone, 1)
            float xj = sZone[2 * ep], yj = sZone[2 * ep + 1];
            bool gyi = yi > cy, gyj = yj > cy;
            if (gyi != gyj) {
                float gx = (xj - xi) * (cy - yi) / (yj - yi) + xi;
                if (gx > cx) cnt++;
            }
        }
        int inz = (((cnt & 1) != 0) && kp) ? 1 : 0;
        out[O1 + bo + t] = (float)inz;
        out[O5 + bo + t] = (float)kp;
    }
}

extern "C" void kernel_launch(void* const* d_in, const int* in_sizes, int n_in,
                              void* d_out, int out_size, void* d_ws, size_t ws_size,
                              hipStream_t stream) {
    const float* pred = (const float*)d_in[0];   // (32,8400,85) fp32
    const float* zone = (const float*)d_in[1];   // (8,2) fp32
    float* out = (float*)d_out;                  // 96000 fp32
    uint32_t* keys = (uint32_t*)d_ws;            // 32*8400 u32 = 1.075 MB

    score_kernel<<<(NB * NA) / 128, 256, 0, stream>>>(pred, keys);
    batch_kernel<<<NB, 1024, 0, stream>>>(pred, zone, keys, out);
}